// Round 10
// baseline (105.402 us; speedup 1.0000x reference)
//
#include <hip/hip_runtime.h>
#include <stdint.h>

typedef unsigned int  u32;
typedef unsigned short u16;

#define B_ROWS 131072
#define P_PRED 64
#define C_CLS  128
#define NPAIR  384               // C*L raw words for dtype detection
#define CAP    32                // max records per predicate (mean 6)
#define RPB    128               // rows per block (2 rows per thread)
#define TPB    512               // 8 waves; wave g owns predicates [8g, 8g+8)
#define GCAP   104               // record capacity per 8-pred group (mean 48)
#define OSTR   33                // u32 stride of transpose-out rows (2-way banks)
#define LOG2E  1.4426950408889634f

#if __has_builtin(__builtin_amdgcn_exp2f)
#define EXP2F(x) __builtin_amdgcn_exp2f(x)
#else
#define EXP2F(x) exp2f(x)
#endif

#if __has_builtin(__builtin_amdgcn_rcpf)
#define RCPF(x) __builtin_amdgcn_rcpf(x)
#else
#define RCPF(x) (1.0f / (x))
#endif

__device__ __forceinline__ float bf16_to_f(u16 u) {
    return __uint_as_float(((u32)u) << 16);
}
__device__ __forceinline__ u16 f_to_bf16(float f) {
    u32 u = __float_as_uint(f);
    u += 0x7FFFu + ((u >> 16) & 1u);   // RNE
    return (u16)(u >> 16);
}
__device__ __forceinline__ u32 pack_bf16x2(float lo, float hi) {
    return (u32)f_to_bf16(lo) | ((u32)f_to_bf16(hi) << 16);
}

// ---------------------------------------------------------------------------
// Prep (validated R9): dtype detection + per-GROUP sorted record streams
// (group = 8 preds = one wave) + packed per-pred byte counts. Record uint2:
//   .x = selfNeg | slot1<<8 | slot2<<16     (slot = 2*idx + neg)
//   .y = bits of sign_self * clamp(w_c,0,500)
// ---------------------------------------------------------------------------
__global__ void ke_prep(const u32* __restrict__ lidx_w,
                        const u32* __restrict__ sb_w,
                        const u32* __restrict__ w_w,
                        uint2* __restrict__ stream,   // [8][GCAP]
                        u32* __restrict__ cnt8w,      // [16] = 64 B
                        u32* __restrict__ flags) {    // [1]: 1 = bf16 floats
    __shared__ int scnt[P_PRED];
    __shared__ u32 recPk[P_PRED][CAP];
    __shared__ float recW[P_PRED][CAP];
    __shared__ int sidx[NPAIR];
    __shared__ int ssb[NPAIR];
    __shared__ int det[3];  // [0] idx-int64, [1] sb-int64, [2] floats-bf16
    const int t = threadIdx.x;
    if (t < P_PRED) scnt[t] = 0;
    if (t < 3) det[t] = 1;
    __syncthreads();
    if (t < NPAIR / 2) {
        if (lidx_w[2 * t + 1] != 0u) det[0] = 0;   // benign race (all write 0)
        if (sb_w[2 * t + 1]   != 0u) det[1] = 0;
    }
    if (t == 0 && (w_w[0] & 0xFFFFu) == 0u) det[2] = 0;
    __syncthreads();
    if (t < NPAIR) {
        sidx[t] = (int)(det[0] ? lidx_w[2 * t] : lidx_w[t]);
        ssb[t]  = (int)(det[1] ? sb_w[2 * t]   : sb_w[t]);
    }
    __syncthreads();
    if (t < NPAIR) {
        const int c = t / 3;
        const int l = t - c * 3;
        const int base = c * 3;
        const int o1 = base + (l == 0 ? 1 : 0);
        const int o2 = base + (l == 2 ? 1 : 2);
        const int p = sidx[t];
        const int slot = atomicAdd(&scnt[p], 1);   // prep-only LDS atomics: fine
        float wraw = det[2] ? bf16_to_f((u16)(w_w[c / 2] >> ((c & 1) * 16)))
                            : __uint_as_float(w_w[c]);
        float wc = fminf(fmaxf(wraw, 0.0f), 500.0f);
        if (slot < CAP) {
            u32 s1 = 2u * (u32)sidx[o1] + (ssb[o1] ? 0u : 1u);
            u32 s2 = 2u * (u32)sidx[o2] + (ssb[o2] ? 0u : 1u);
            recPk[p][slot] = (ssb[t] ? 0u : 1u) | (s1 << 8) | (s2 << 16);
            recW[p][slot]  = ssb[t] ? wc : -wc;
        }
    }
    __syncthreads();
    if (t < P_PRED) {
        const int p = t;
        const int g = p >> 3;
        const int n = min(scnt[p], CAP);
        int off = 0;
        for (int pb = g * 8; pb < p; ++pb) off += min(scnt[pb], CAP);
        int ncl = 0;
        for (int j = 0; j < n; ++j) {
            if (off + j < GCAP) {
                stream[g * GCAP + off + j] =
                    make_uint2(recPk[p][j], __float_as_uint(recW[p][j]));
                ++ncl;
            }
        }
        ((unsigned char*)cnt8w)[p] = (unsigned char)ncl;
    }
    if (t == 0) flags[0] = (u32)det[2];
}

// ---------------------------------------------------------------------------
// Main: bf16 both-signs E2[slot][row] (128x128 u16, 32 KB; u32 = row pair)
// staged with PAIRED b32 writes; records in LDS (R9); record loop unrolled
// x4 with dual accumulators; epilogue re-uses dead E2 space as a stride-33
// transpose buffer -> fully-coalesced 32 B/lane global stores (R9 stored at
// 512-B stride: 2x write amplification, WRITE_SIZE 33.5 MB for 16.8 logical).
// 39.5 KB LDS -> 4 blocks/CU x 8 waves = 32 waves/CU; grid = 1024 blocks.
// ---------------------------------------------------------------------------
__global__ __launch_bounds__(TPB, 8)
void ke_main(const void* __restrict__ atoms_v,
             const uint2* __restrict__ stream_g,
             const u32* __restrict__ cnt8w,
             const u32* __restrict__ flags,
             void* __restrict__ out_v) {
    __shared__ u32 smem32[8192];              // 32 KB: E2 table, then OutT
    __shared__ uint2 srec[8 * GCAP];          // 6656 B
    __shared__ unsigned char cnt8[P_PRED];    // 64 B
    u16* E2 = (u16*)smem32;                   // [slot][128 rows] bf16
    const int tid = threadIdx.x;
    const int lane = tid & 63;
    const int g = __builtin_amdgcn_readfirstlane(tid >> 6);  // 0..7, SGPR
    const int rowBase = blockIdx.x * RPB;
    const bool bf16m = (flags[0] != 0u);

    // ---- copy record streams + counts to LDS (coalesced, overlaps staging)
    for (int i = tid; i < 8 * GCAP; i += TPB) srec[i] = stream_g[i];
    if (tid < 16) ((u32*)cnt8)[tid] = cnt8w[tid];

    // ---- stage E2: thread owns row pair (2a, 2a+1), 8-atom chunk c0.
    //      One u32 (both rows) per slot: 16 ds_write_b32 (vs 32 b16 in R9).
    {
        const int a = tid & 63;
        const int c0 = (tid >> 6) * 8;
        if (bf16m) {
            const u16* gp0 = (const u16*)atoms_v + (size_t)(rowBase + 2 * a) * P_PRED + c0;
            uint4 v0 = *(const uint4*)gp0;            // row 2a, 8 bf16
            uint4 v1 = *(const uint4*)(gp0 + P_PRED); // row 2a+1, 8 bf16
            u32 w0[4] = {v0.x, v0.y, v0.z, v0.w};
            u32 w1[4] = {v1.x, v1.y, v1.z, v1.w};
#pragma unroll
            for (int k = 0; k < 4; ++k) {
                float xl0 = __uint_as_float(w0[k] << 16) * LOG2E;          // atom c0+2k, row 2a
                float xh0 = __uint_as_float(w0[k] & 0xFFFF0000u) * LOG2E;  // atom c0+2k+1
                float xl1 = __uint_as_float(w1[k] << 16) * LOG2E;          // row 2a+1
                float xh1 = __uint_as_float(w1[k] & 0xFFFF0000u) * LOG2E;
                float el0 = EXP2F(xl0), eh0 = EXP2F(xh0);
                float el1 = EXP2F(xl1), eh1 = EXP2F(xh1);
                const int m = c0 + 2 * k;
                smem32[(2 * m)     * 64 + a] = pack_bf16x2(el0, el1);
                smem32[(2 * m + 1) * 64 + a] = pack_bf16x2(RCPF(el0), RCPF(el1));
                smem32[(2 * m + 2) * 64 + a] = pack_bf16x2(eh0, eh1);
                smem32[(2 * m + 3) * 64 + a] = pack_bf16x2(RCPF(eh0), RCPF(eh1));
            }
        } else {
            const float* gp0 = (const float*)atoms_v + (size_t)(rowBase + 2 * a) * P_PRED + c0;
            float4 u0 = *(const float4*)gp0;
            float4 u1 = *(const float4*)(gp0 + 4);
            float4 d0 = *(const float4*)(gp0 + P_PRED);
            float4 d1 = *(const float4*)(gp0 + P_PRED + 4);
            float r0[8] = {u0.x, u0.y, u0.z, u0.w, u1.x, u1.y, u1.z, u1.w};
            float r1[8] = {d0.x, d0.y, d0.z, d0.w, d1.x, d1.y, d1.z, d1.w};
#pragma unroll
            for (int k = 0; k < 8; ++k) {
                float e0 = EXP2F(r0[k] * LOG2E);
                float e1 = EXP2F(r1[k] * LOG2E);
                const int m = c0 + k;
                smem32[(2 * m)     * 64 + a] = pack_bf16x2(e0, e1);
                smem32[(2 * m + 1) * 64 + a] = pack_bf16x2(RCPF(e0), RCPF(e1));
            }
        }
    }
    __syncthreads();

    const int q2 = 2 * lane;               // u16 row index of this row pair
    float2 acc[8];
    int j = g * GCAP;                      // stream cursor

#pragma unroll
    for (int pp = 0; pp < 8; ++pp) {
        const int p = g * 8 + pp;                        // wave-uniform
        const u32 eppv = *(const u32*)&E2[(2 * p)     * RPB + q2];
        const u32 epnv = *(const u32*)&E2[(2 * p + 1) * RPB + q2];
        const float eppx = __uint_as_float(eppv << 16);
        const float eppy = __uint_as_float(eppv & 0xFFFF0000u);
        const float epnx = __uint_as_float(epnv << 16);
        const float epny = __uint_as_float(epnv & 0xFFFF0000u);
        const int n = (int)cnt8[p];
        float2 a0 = make_float2(0.0f, 0.0f);
        float2 a1 = make_float2(0.0f, 0.0f);

#define REC_BODY(J, A)                                                        \
        {                                                                     \
            const uint2 rec = srec[J];                 /* b64 broadcast */    \
            const u32 pk = rec.x;                                             \
            const float sw = __uint_as_float(rec.y);                          \
            const u32 s1v = *(const u32*)&E2[(int)((pk >> 8)  & 255u) * RPB + q2]; \
            const u32 s2v = *(const u32*)&E2[(int)((pk >> 16) & 255u) * RPB + q2]; \
            const float ssx = (pk & 1u) ? epnx : eppx;                        \
            const float ssy = (pk & 1u) ? epny : eppy;                        \
            const float s1x = __uint_as_float(s1v << 16);                     \
            const float s1y = __uint_as_float(s1v & 0xFFFF0000u);             \
            const float s2x = __uint_as_float(s2v << 16);                     \
            const float s2y = __uint_as_float(s2v & 0xFFFF0000u);             \
            const float tx = RCPF(ssx + s1x + s2x);                           \
            const float ty = RCPF(ssy + s1y + s2y);                          \
            A.x = fmaf(sw * ssx, tx, A.x);                                    \
            A.y = fmaf(sw * ssy, ty, A.y);                                    \
        }

        int e = 0;
        for (; e + 3 < n; e += 4) {        // unroll x4, dual accumulators
            REC_BODY(j,     a0)
            REC_BODY(j + 1, a1)
            REC_BODY(j + 2, a0)
            REC_BODY(j + 3, a1)
            j += 4;
        }
        for (; e < n; ++e, ++j) REC_BODY(j, a0)
#undef REC_BODY
        acc[pp] = make_float2(a0.x + a1.x, a0.y + a1.y);
    }

    if (bf16m) {
        // ---- epilogue: transpose via dead E2 space, then coalesced stores
        __syncthreads();   // all waves done reading E2/srec
        u32* OutT = smem32;   // [row][OSTR] u32 (= 2 bf16 cols), 16.9 KB
#pragma unroll
        for (int k = 0; k < 4; ++k) {
            u32 lo = pack_bf16x2(acc[2 * k].x, acc[2 * k + 1].x); // row 2q
            u32 hi = pack_bf16x2(acc[2 * k].y, acc[2 * k + 1].y); // row 2q+1
            OutT[(q2)     * OSTR + g * 4 + k] = lo;
            OutT[(q2 + 1) * OSTR + g * 4 + k] = hi;
        }
        __syncthreads();
        const int erow = tid >> 2;
        const int qt = tid & 3;
        const u32* src = &OutT[erow * OSTR + qt * 8];
        uint4 o0 = make_uint4(src[0], src[1], src[2], src[3]);
        uint4 o1 = make_uint4(src[4], src[5], src[6], src[7]);
        u16* op = (u16*)out_v + (size_t)(rowBase + erow) * P_PRED + qt * 16;
        *(uint4*)op       = o0;
        *(uint4*)(op + 8) = o1;
    } else {
        float* op0 = (float*)out_v + (size_t)(rowBase + q2) * P_PRED + g * 8;
        float* op1 = op0 + P_PRED;
        *(float4*)(op0)     = make_float4(acc[0].x, acc[1].x, acc[2].x, acc[3].x);
        *(float4*)(op0 + 4) = make_float4(acc[4].x, acc[5].x, acc[6].x, acc[7].x);
        *(float4*)(op1)     = make_float4(acc[0].y, acc[1].y, acc[2].y, acc[3].y);
        *(float4*)(op1 + 4) = make_float4(acc[4].y, acc[5].y, acc[6].y, acc[7].y);
    }
}

extern "C" void kernel_launch(void* const* d_in, const int* in_sizes, int n_in,
                              void* d_out, int out_size, void* d_ws, size_t ws_size,
                              hipStream_t stream_h) {
    const u32* clause_weights = (const u32*)d_in[1]; // bf16 or f32 [128]
    const u32* literal_idx    = (const u32*)d_in[2]; // int32 or int64 [128,3]
    const u32* sign_bits      = (const u32*)d_in[3]; // int32 or int64 [128,3]

    uint2* stream = (uint2*)d_ws;                          // 8*104*8 = 6656 B
    u32*   cnt8w  = (u32*)((char*)d_ws + 8 * GCAP * 8);    // 64 B
    u32*   flags  = (u32*)((char*)d_ws + 8 * GCAP * 8 + 64);

    ke_prep<<<1, NPAIR, 0, stream_h>>>(literal_idx, sign_bits, clause_weights,
                                       stream, cnt8w, flags);
    ke_main<<<B_ROWS / RPB, TPB, 0, stream_h>>>(d_in[0], stream, cnt8w, flags,
                                                d_out);
}

// Round 11
// 102.645 us; speedup vs baseline: 1.0269x; 1.0269x over previous
//
#include <hip/hip_runtime.h>
#include <stdint.h>

typedef unsigned int  u32;
typedef unsigned short u16;

#define B_ROWS 131072
#define P_PRED 64
#define C_CLS  128
#define NPAIR  384               // C*L raw words for dtype detection
#define CAP    32                // max records per predicate (mean 6)
#define RPB    128               // rows per block (2 rows per thread)
#define TPB    512               // 8 waves; wave g owns predicates [8g, 8g+8)
#define GCAP   104               // record capacity per 8-pred group (mean 48)
#define LOG2E  1.4426950408889634f

#if __has_builtin(__builtin_amdgcn_exp2f)
#define EXP2F(x) __builtin_amdgcn_exp2f(x)
#else
#define EXP2F(x) exp2f(x)
#endif

#if __has_builtin(__builtin_amdgcn_rcpf)
#define RCPF(x) __builtin_amdgcn_rcpf(x)
#else
#define RCPF(x) (1.0f / (x))
#endif

__device__ __forceinline__ float bf16_to_f(u16 u) {
    return __uint_as_float(((u32)u) << 16);
}
__device__ __forceinline__ u16 f_to_bf16(float f) {
    u32 u = __float_as_uint(f);
    u += 0x7FFFu + ((u >> 16) & 1u);   // RNE
    return (u16)(u >> 16);
}
__device__ __forceinline__ u32 pack_bf16x2(float lo, float hi) {
    return (u32)f_to_bf16(lo) | ((u32)f_to_bf16(hi) << 16);
}

// ---------------------------------------------------------------------------
// SINGLE fused kernel. Every block:
//   phase 0: inline prep (R9-validated logic) in LDS — dtype detection,
//            per-predicate CSR, per-GROUP sorted record streams + counts.
//            Inputs ~3.3 KB, L2-broadcast; LDS-atomic build ~0.5 us; fully
//            parallel across blocks (vs R10's serial 1-block prep kernel +
//            global round-trip + launch dependency).
//   phase 1: bf16 both-signs E2[slot][row] staged into the SAME 32 KB LDS
//            (prep scratch is dead), paired-row b32 writes.
//   phase 2: record loop (R9 structure: LDS records, no atomics, no
//            readlane, no s_load chains; unroll x4, dual accumulators).
//   phase 3: direct stores (R9 epilogue; R10's transpose regressed).
// LDS = 32 KB + 6.7 KB -> 4 blocks/CU x 8 waves = 32 waves/CU.
// Workspace d_ws: UNUSED.
// ---------------------------------------------------------------------------
__global__ __launch_bounds__(TPB, 8)
void ke_fused(const u32* __restrict__ lidx_w,
              const u32* __restrict__ sb_w,
              const u32* __restrict__ w_w,
              const void* __restrict__ atoms_v,
              void* __restrict__ out_v) {
    __shared__ u32 S[8192];                   // 32 KB: prep scratch, then E2
    __shared__ uint2 srec[8 * GCAP];          // 6656 B (persists all phases)
    __shared__ unsigned char cnt8[P_PRED];    // 64 B
    u16* E2 = (u16*)S;                        // [slot][128 rows] bf16

    const int tid = threadIdx.x;
    const int lane = tid & 63;
    const int g = __builtin_amdgcn_readfirstlane(tid >> 6);  // 0..7, SGPR
    const int rowBase = blockIdx.x * RPB;

    // ======== phase 0: inline prep (scratch aliased into S) ========
    int*   scnt  = (int*)&S[0];       // [64]
    int*   det   = (int*)&S[64];      // [3]
    int*   sidx  = (int*)&S[128];     // [384]
    int*   ssb   = (int*)&S[512];     // [384]
    u32*   recPk = &S[1024];          // [64][32]
    float* recW  = (float*)&S[3072];  // [64][32]

    if (tid < P_PRED) scnt[tid] = 0;
    if (tid < 3) det[tid] = 1;
    __syncthreads();
    if (tid < NPAIR / 2) {
        if (lidx_w[2 * tid + 1] != 0u) det[0] = 0;   // benign race (all write 0)
        if (sb_w[2 * tid + 1]   != 0u) det[1] = 0;
    }
    if (tid == 0 && (w_w[0] & 0xFFFFu) == 0u) det[2] = 0;
    __syncthreads();
    if (tid < NPAIR) {
        sidx[tid] = (int)(det[0] ? lidx_w[2 * tid] : lidx_w[tid]);
        ssb[tid]  = (int)(det[1] ? sb_w[2 * tid]   : sb_w[tid]);
    }
    __syncthreads();
    const bool bf16m = (det[2] != 0);            // latch before S is reused
    if (tid < NPAIR) {
        const int c = tid / 3;
        const int l = tid - c * 3;
        const int base = c * 3;
        const int o1 = base + (l == 0 ? 1 : 0);
        const int o2 = base + (l == 2 ? 1 : 2);
        const int p = sidx[tid];
        const int slot = atomicAdd(&scnt[p], 1); // prep-only LDS atomics: fine
        float wraw = bf16m ? bf16_to_f((u16)(w_w[c / 2] >> ((c & 1) * 16)))
                           : __uint_as_float(w_w[c]);
        float wc = fminf(fmaxf(wraw, 0.0f), 500.0f);
        if (slot < CAP) {
            u32 s1 = 2u * (u32)sidx[o1] + (ssb[o1] ? 0u : 1u);
            u32 s2 = 2u * (u32)sidx[o2] + (ssb[o2] ? 0u : 1u);
            recPk[p * CAP + slot] = (ssb[tid] ? 0u : 1u) | (s1 << 8) | (s2 << 16);
            recW[p * CAP + slot]  = ssb[tid] ? wc : -wc;
        }
    }
    __syncthreads();
    if (tid < P_PRED) {
        const int p = tid;
        const int gg = p >> 3;
        const int n = min(scnt[p], CAP);
        int off = 0;
        for (int pb = gg * 8; pb < p; ++pb) off += min(scnt[pb], CAP);
        int ncl = 0;
        for (int j = 0; j < n; ++j) {
            if (off + j < GCAP) {
                srec[gg * GCAP + off + j] =
                    make_uint2(recPk[p * CAP + j], __float_as_uint(recW[p * CAP + j]));
                ++ncl;
            }
        }
        cnt8[p] = (unsigned char)ncl;
    }
    __syncthreads();   // srec/cnt8 ready; prep scratch in S now dead

    // ======== phase 1: stage E2 (paired-row b32 writes) ========
    {
        const int a = tid & 63;                  // row pair (2a, 2a+1)
        const int c0 = (tid >> 6) * 8;           // 8-atom chunk
        if (bf16m) {
            const u16* gp0 = (const u16*)atoms_v + (size_t)(rowBase + 2 * a) * P_PRED + c0;
            uint4 v0 = *(const uint4*)gp0;            // row 2a
            uint4 v1 = *(const uint4*)(gp0 + P_PRED); // row 2a+1
            u32 w0[4] = {v0.x, v0.y, v0.z, v0.w};
            u32 w1[4] = {v1.x, v1.y, v1.z, v1.w};
#pragma unroll
            for (int k = 0; k < 4; ++k) {
                float xl0 = __uint_as_float(w0[k] << 16) * LOG2E;
                float xh0 = __uint_as_float(w0[k] & 0xFFFF0000u) * LOG2E;
                float xl1 = __uint_as_float(w1[k] << 16) * LOG2E;
                float xh1 = __uint_as_float(w1[k] & 0xFFFF0000u) * LOG2E;
                float el0 = EXP2F(xl0), eh0 = EXP2F(xh0);
                float el1 = EXP2F(xl1), eh1 = EXP2F(xh1);
                const int m = c0 + 2 * k;
                S[(2 * m)     * 64 + a] = pack_bf16x2(el0, el1);
                S[(2 * m + 1) * 64 + a] = pack_bf16x2(RCPF(el0), RCPF(el1));
                S[(2 * m + 2) * 64 + a] = pack_bf16x2(eh0, eh1);
                S[(2 * m + 3) * 64 + a] = pack_bf16x2(RCPF(eh0), RCPF(eh1));
            }
        } else {
            const float* gp0 = (const float*)atoms_v + (size_t)(rowBase + 2 * a) * P_PRED + c0;
            float4 u0 = *(const float4*)gp0;
            float4 u1 = *(const float4*)(gp0 + 4);
            float4 d0 = *(const float4*)(gp0 + P_PRED);
            float4 d1 = *(const float4*)(gp0 + P_PRED + 4);
            float r0[8] = {u0.x, u0.y, u0.z, u0.w, u1.x, u1.y, u1.z, u1.w};
            float r1[8] = {d0.x, d0.y, d0.z, d0.w, d1.x, d1.y, d1.z, d1.w};
#pragma unroll
            for (int k = 0; k < 8; ++k) {
                float e0 = EXP2F(r0[k] * LOG2E);
                float e1 = EXP2F(r1[k] * LOG2E);
                const int m = c0 + k;
                S[(2 * m)     * 64 + a] = pack_bf16x2(e0, e1);
                S[(2 * m + 1) * 64 + a] = pack_bf16x2(RCPF(e0), RCPF(e1));
            }
        }
    }
    __syncthreads();

    // ======== phase 2: record loop ========
    const int q2 = 2 * lane;               // u16 row index of this row pair
    float2 acc[8];
    int j = g * GCAP;                      // stream cursor

#pragma unroll
    for (int pp = 0; pp < 8; ++pp) {
        const int p = g * 8 + pp;                        // wave-uniform
        const u32 eppv = *(const u32*)&E2[(2 * p)     * RPB + q2];
        const u32 epnv = *(const u32*)&E2[(2 * p + 1) * RPB + q2];
        const float eppx = __uint_as_float(eppv << 16);
        const float eppy = __uint_as_float(eppv & 0xFFFF0000u);
        const float epnx = __uint_as_float(epnv << 16);
        const float epny = __uint_as_float(epnv & 0xFFFF0000u);
        const int n = (int)cnt8[p];
        float2 a0 = make_float2(0.0f, 0.0f);
        float2 a1 = make_float2(0.0f, 0.0f);

#define REC_BODY(J, A)                                                        \
        {                                                                     \
            const uint2 rec = srec[J];                 /* b64 broadcast */    \
            const u32 pk = rec.x;                                             \
            const float sw = __uint_as_float(rec.y);                          \
            const u32 s1v = *(const u32*)&E2[(int)((pk >> 8)  & 255u) * RPB + q2]; \
            const u32 s2v = *(const u32*)&E2[(int)((pk >> 16) & 255u) * RPB + q2]; \
            const float ssx = (pk & 1u) ? epnx : eppx;                        \
            const float ssy = (pk & 1u) ? epny : eppy;                        \
            const float s1x = __uint_as_float(s1v << 16);                     \
            const float s1y = __uint_as_float(s1v & 0xFFFF0000u);             \
            const float s2x = __uint_as_float(s2v << 16);                     \
            const float s2y = __uint_as_float(s2v & 0xFFFF0000u);             \
            const float tx = RCPF(ssx + s1x + s2x);                           \
            const float ty = RCPF(ssy + s1y + s2y);                          \
            A.x = fmaf(sw * ssx, tx, A.x);                                    \
            A.y = fmaf(sw * ssy, ty, A.y);                                    \
        }

        int e = 0;
        for (; e + 3 < n; e += 4) {        // unroll x4, dual accumulators
            REC_BODY(j,     a0)
            REC_BODY(j + 1, a1)
            REC_BODY(j + 2, a0)
            REC_BODY(j + 3, a1)
            j += 4;
        }
        for (; e < n; ++e, ++j) REC_BODY(j, a0)
#undef REC_BODY
        acc[pp] = make_float2(a0.x + a1.x, a0.y + a1.y);
    }

    // ======== phase 3: direct stores (R9 epilogue) ========
    if (bf16m) {
        u16* op0 = (u16*)out_v + (size_t)(rowBase + q2) * P_PRED + g * 8;
        u16* op1 = op0 + P_PRED;
        uint4 o0, o1v;
        o0.x  = pack_bf16x2(acc[0].x, acc[1].x);
        o0.y  = pack_bf16x2(acc[2].x, acc[3].x);
        o0.z  = pack_bf16x2(acc[4].x, acc[5].x);
        o0.w  = pack_bf16x2(acc[6].x, acc[7].x);
        o1v.x = pack_bf16x2(acc[0].y, acc[1].y);
        o1v.y = pack_bf16x2(acc[2].y, acc[3].y);
        o1v.z = pack_bf16x2(acc[4].y, acc[5].y);
        o1v.w = pack_bf16x2(acc[6].y, acc[7].y);
        *(uint4*)op0 = o0;
        *(uint4*)op1 = o1v;
    } else {
        float* op0 = (float*)out_v + (size_t)(rowBase + q2) * P_PRED + g * 8;
        float* op1 = op0 + P_PRED;
        *(float4*)(op0)     = make_float4(acc[0].x, acc[1].x, acc[2].x, acc[3].x);
        *(float4*)(op0 + 4) = make_float4(acc[4].x, acc[5].x, acc[6].x, acc[7].x);
        *(float4*)(op1)     = make_float4(acc[0].y, acc[1].y, acc[2].y, acc[3].y);
        *(float4*)(op1 + 4) = make_float4(acc[4].y, acc[5].y, acc[6].y, acc[7].y);
    }
}

extern "C" void kernel_launch(void* const* d_in, const int* in_sizes, int n_in,
                              void* d_out, int out_size, void* d_ws, size_t ws_size,
                              hipStream_t stream_h) {
    const u32* clause_weights = (const u32*)d_in[1]; // bf16 or f32 [128]
    const u32* literal_idx    = (const u32*)d_in[2]; // int32 or int64 [128,3]
    const u32* sign_bits      = (const u32*)d_in[3]; // int32 or int64 [128,3]
    (void)d_ws; (void)ws_size;                       // workspace unused

    ke_fused<<<B_ROWS / RPB, TPB, 0, stream_h>>>(literal_idx, sign_bits,
                                                 clause_weights, d_in[0],
                                                 d_out);
}